// Round 3
// baseline (105.219 us; speedup 1.0000x reference)
//
#include <hip/hip_runtime.h>
#include <hip/hip_bf16.h>
#include <stdint.h>

#define S_LEN 2048
#define BATCH 4
#define HID 1024
#define M_ROWS (BATCH * S_LEN)   // 8192

typedef __attribute__((ext_vector_type(8))) short short8;
typedef __attribute__((ext_vector_type(4))) float f32x4;

__device__ __forceinline__ void gload_lds16(const __hip_bfloat16* g,
                                            __hip_bfloat16* l) {
  __builtin_amdgcn_global_load_lds(
      (const __attribute__((address_space(1))) unsigned int*)g,
      (__attribute__((address_space(3))) unsigned int*)l, 16, 0, 0);
}

template <int N>
__device__ __forceinline__ void wait_vm() {
  if constexpr (N == 0)
    asm volatile("s_waitcnt vmcnt(0)" ::: "memory");
  else if constexpr (N == 2)
    asm volatile("s_waitcnt vmcnt(2)" ::: "memory");
  else
    asm volatile("s_waitcnt vmcnt(4)" ::: "memory");
}

// ============ transpose-convert: Wq,Wk fp32 -> WqT,WkT bf16 ============
__global__ __launch_bounds__(256) void transpose_convert(
    const float* __restrict__ Wq, const float* __restrict__ Wk,
    __hip_bfloat16* __restrict__ WqT, __hip_bfloat16* __restrict__ WkT) {
  __shared__ float tile[32][33];
  const float* src = blockIdx.z ? Wk : Wq;
  __hip_bfloat16* dst = blockIdx.z ? WkT : WqT;
  const int tx = threadIdx.x & 31, ty = threadIdx.x >> 5;  // ty 0..7
  const int r0 = blockIdx.y * 32, c0 = blockIdx.x * 32;
#pragma unroll
  for (int rr = 0; rr < 4; ++rr) {
    const int r = ty + rr * 8;
    tile[r][tx] = src[(size_t)(r0 + r) * HID + c0 + tx];
  }
  __syncthreads();
#pragma unroll
  for (int rr = 0; rr < 4; ++rr) {
    const int r = ty + rr * 8;
    dst[(size_t)(c0 + r) * HID + r0 + tx] = __float2bfloat16(tile[tx][r]);
  }
}

// ============ bias stage 1: a1 = Wq^T bk, a2 = Wk^T bq, c = bq.bk ======
__global__ __launch_bounds__(256) void bias_stage1(
    const __hip_bfloat16* __restrict__ WqT,
    const __hip_bfloat16* __restrict__ WkT, const float* __restrict__ bq,
    const float* __restrict__ bk, float* __restrict__ a1,
    float* __restrict__ a2, float* __restrict__ cbuf) {
  const int g = blockIdx.x * 4 + (threadIdx.x >> 6);  // wave 0..2047
  const int l = threadIdx.x & 63;
  const int mat = g & 1;
  const int j = g >> 1;
  const __hip_bfloat16* W = mat ? WkT : WqT;
  const float* bv = mat ? bq : bk;
  float s = 0.f;
#pragma unroll
  for (int e = 0; e < 16; ++e)
    s += __bfloat162float(W[(size_t)j * HID + l * 16 + e]) * bv[l * 16 + e];
#pragma unroll
  for (int m = 1; m < 64; m <<= 1) s += __shfl_xor(s, m, 64);
  if (l == 0) (mat ? a2 : a1)[j] = s;
  if (blockIdx.x == 0 && threadIdx.x < 64) {
    float cs = 0.f;
#pragma unroll
    for (int e = 0; e < 16; ++e)
      cs += bq[threadIdx.x * 16 + e] * bk[threadIdx.x * 16 + e];
#pragma unroll
    for (int m = 1; m < 64; m <<= 1) cs += __shfl_xor(cs, m, 64);
    if (threadIdx.x == 0) cbuf[0] = cs;
  }
}

// ===== convert hs -> bf16, plus u = hs.a1 + c (row term), w = hs.a2 =====
// grid: one block per row (8192 blocks x 256 thr, 4 cols/thread)
__global__ __launch_bounds__(256) void convert_hs(
    const float* __restrict__ hs, const float* __restrict__ a1,
    const float* __restrict__ a2, const float* __restrict__ cbuf,
    __hip_bfloat16* __restrict__ hs_bf, float* __restrict__ u,
    float* __restrict__ w) {
  const int i = blockIdx.x;
  const int t = threadIdx.x;
  float4 v = *reinterpret_cast<const float4*>(hs + (size_t)i * HID + t * 4);
  __hip_bfloat16 tmp[4] = {__float2bfloat16(v.x), __float2bfloat16(v.y),
                           __float2bfloat16(v.z), __float2bfloat16(v.w)};
  *reinterpret_cast<ushort4*>(hs_bf + (size_t)i * HID + t * 4) =
      *reinterpret_cast<const ushort4*>(tmp);
  float4 A1 = *reinterpret_cast<const float4*>(a1 + t * 4);
  float4 A2 = *reinterpret_cast<const float4*>(a2 + t * 4);
  float pu = v.x * A1.x + v.y * A1.y + v.z * A1.z + v.w * A1.w;
  float pw = v.x * A2.x + v.y * A2.y + v.z * A2.z + v.w * A2.w;
#pragma unroll
  for (int m = 1; m < 64; m <<= 1) {
    pu += __shfl_xor(pu, m, 64);
    pw += __shfl_xor(pw, m, 64);
  }
  __shared__ float su[4], sw[4];
  if ((t & 63) == 0) { su[t >> 6] = pu; sw[t >> 6] = pw; }
  __syncthreads();
  if (t == 0) {
    u[i] = su[0] + su[1] + su[2] + su[3] + cbuf[0];
    w[i] = sw[0] + sw[1] + sw[2] + sw[3];
  }
}

// ================= templated 8-phase NT GEMM core =====================
// BM=256 fixed; BN = NF*64 (NF=4 -> 256, NF=2 -> 128). 512 thr = 8 waves
// (2 M x 4 N); per-wave output 128 x (NF*16). Double-buffered LDS,
// XOR-swizzle (16B slot ^= row&7) both sides, counted vmcnt, setprio.
template <int NT, int NF>
__device__ __forceinline__ void gemm_core(
    const __hip_bfloat16* __restrict__ A, const __hip_bfloat16* __restrict__ B,
    const int lda, const int ldb, __hip_bfloat16* lds, f32x4 acc[8][NF]) {
  constexpr int NH = NF / 2;   // frags per n-half (2 or 1); also B 128-row units
  const int t = threadIdx.x;
  const int wid = t >> 6;
  const int l = t & 63;
  const int lr = l & 15;
  const int lk = l >> 4;
  const int wr = wid >> 2;
  const int wc = wid & 3;
  const int trow = t >> 3;
  const int tslot = (t & 7) ^ (trow & 7);
  const int rsx = lr & 7;

  __hip_bfloat16* const A0 = lds;
  __hip_bfloat16* const A1 = lds + 16384;
  __hip_bfloat16* const B0 = lds + 32768;
  __hip_bfloat16* const B1 = B0 + NF * 64 * 64;

  short8 fa[4][2], fb[NF][2];

#define STAGE_U(lb, gb, ld, half, kt) do {                                    \
    gload_lds16((gb) + (size_t)((half)*128 + 0  + trow) * (ld) + (kt)*64 +    \
                    tslot * 8,                                                \
                (lb) + ((half)*128 + 0) * 64 + wid * 512);                    \
    gload_lds16((gb) + (size_t)((half)*128 + 64 + trow) * (ld) + (kt)*64 +    \
                    tslot * 8,                                                \
                (lb) + ((half)*128 + 64) * 64 + wid * 512);                   \
  } while (0)

#define LDA_H(mh, Ac) do {                                                    \
    _Pragma("unroll") for (int m = 0; m < 4; ++m)                             \
    _Pragma("unroll") for (int kk = 0; kk < 2; ++kk)                          \
      fa[m][kk] = *reinterpret_cast<const short8*>(                           \
          (Ac) + (wr * 128 + (mh)*64 + m * 16 + lr) * 64 +                    \
          (((kk * 4 + lk) ^ rsx) * 8));                                       \
  } while (0)

#define LDB_H(nh, Bc) do {                                                    \
    _Pragma("unroll") for (int n = 0; n < NH; ++n)                            \
    _Pragma("unroll") for (int kk = 0; kk < 2; ++kk)                          \
      fb[(nh)*NH + n][kk] = *reinterpret_cast<const short8*>(                 \
          (Bc) + (wc * (NF * 16) + (nh) * (NH * 16) + n * 16 + lr) * 64 +     \
          (((kk * 4 + lk) ^ rsx) * 8));                                       \
  } while (0)

#define MFMA_Q(mh, nh) do {                                                   \
    __builtin_amdgcn_s_setprio(1);                                            \
    _Pragma("unroll") for (int m = 0; m < 4; ++m)                             \
    _Pragma("unroll") for (int n = 0; n < NH; ++n)                            \
    _Pragma("unroll") for (int kk = 0; kk < 2; ++kk)                          \
      acc[(mh)*4 + m][(nh)*NH + n] = __builtin_amdgcn_mfma_f32_16x16x32_bf16( \
          fa[m][kk], fb[(nh)*NH + n][kk], acc[(mh)*4 + m][(nh)*NH + n],       \
          0, 0, 0);                                                           \
    __builtin_amdgcn_s_setprio(0);                                            \
  } while (0)

#define CFENCE asm volatile("" ::: "memory")
#define BAR_PRE do { CFENCE; __builtin_amdgcn_s_barrier();                    \
    asm volatile("s_waitcnt lgkmcnt(0)" ::: "memory"); } while (0)
#define BAR_POST do { CFENCE; __builtin_amdgcn_s_barrier(); CFENCE; } while (0)

  // prologue: tile0 fully, tile1 B
  STAGE_U(A0, A, lda, 0, 0); STAGE_U(A0, A, lda, 1, 0);
  STAGE_U(B0, B, ldb, 0, 0); if (NH == 2) STAGE_U(B0, B, ldb, 1, 0);
  STAGE_U(B1, B, ldb, 0, 1); if (NH == 2) STAGE_U(B1, B, ldb, 1, 1);
  wait_vm<2 * NH>();
  __builtin_amdgcn_s_barrier();
  CFENCE;

#pragma unroll 2
  for (int tt = 0; tt < NT; ++tt) {
    const int cur = tt & 1;
    __hip_bfloat16* const Ac = cur ? A1 : A0;
    __hip_bfloat16* const An = cur ? A0 : A1;
    __hip_bfloat16* const Bc = cur ? B1 : B0;
    // c0
    LDA_H(0, Ac); LDB_H(0, Bc);
    if (tt + 1 < NT) STAGE_U(An, A, lda, 0, tt + 1);
    BAR_PRE; MFMA_Q(0, 0); BAR_POST;
    // c1
    LDB_H(1, Bc);
    if (tt + 1 < NT) STAGE_U(An, A, lda, 1, tt + 1);
    BAR_PRE; MFMA_Q(0, 1); BAR_POST;
    // c2
    LDA_H(1, Ac);
    if (tt + 2 < NT) STAGE_U(Bc, B, ldb, 0, tt + 2);
    BAR_PRE; MFMA_Q(1, 1); BAR_POST;
    // c3 (tail: drain fully so next tile's A never races)
    if (NH == 2 && tt + 2 < NT) STAGE_U(Bc, B, ldb, 1, tt + 2);
    BAR_PRE; MFMA_Q(1, 0);
    if (tt + 2 < NT) wait_vm<2 * NH>(); else wait_vm<0>();
    BAR_POST;
  }
#undef STAGE_U
#undef LDA_H
#undef LDB_H
#undef MFMA_Q
#undef CFENCE
#undef BAR_PRE
#undef BAR_POST
}

// ===== wmid partial: part[kz] = WkT[:,kz*256:+256] . WqT^T slice ======
// grid (4,4,4): out tile 256x256, K-slab 256 (NT=4)
__global__ __launch_bounds__(512, 2) void wmid_gemm(
    const __hip_bfloat16* __restrict__ WkT,
    const __hip_bfloat16* __restrict__ WqT, float* __restrict__ part) {
  extern __shared__ char smem[];
  __hip_bfloat16* lds = reinterpret_cast<__hip_bfloat16*>(smem);
  const int kz = blockIdx.z;
  f32x4 acc[8][4];
#pragma unroll
  for (int m = 0; m < 8; ++m)
#pragma unroll
    for (int n = 0; n < 4; ++n) acc[m][n] = (f32x4){0.f, 0.f, 0.f, 0.f};

  gemm_core<4, 4>(WkT + (size_t)blockIdx.y * 256 * HID + kz * 256,
                  WqT + (size_t)blockIdx.x * 256 * HID + kz * 256, HID, HID,
                  lds, acc);

  float* outp = part + (size_t)kz * (HID * HID);
  const int t = threadIdx.x, wid = t >> 6, l = t & 63;
  const int wr = wid >> 2, wcn = wid & 3;
  const int lr = l & 15, lg = l >> 4;
#pragma unroll
  for (int m = 0; m < 8; ++m)
#pragma unroll
    for (int n = 0; n < 4; ++n) {
      const int col = blockIdx.x * 256 + wcn * 64 + n * 16 + lr;
#pragma unroll
      for (int r = 0; r < 4; ++r) {
        const int row = blockIdx.y * 256 + wr * 128 + m * 16 + lg * 4 + r;
        outp[(size_t)row * HID + col] = acc[m][n][r];
      }
    }
}

// ============ reduce 4 slabs -> wmid bf16 ============
__global__ __launch_bounds__(256) void wmid_reduce(
    const float* __restrict__ part, __hip_bfloat16* __restrict__ wmid_bf) {
  const int idx = (blockIdx.x * 256 + threadIdx.x) * 4;
  float4 s0 = *reinterpret_cast<const float4*>(part + idx);
  float4 s1 = *reinterpret_cast<const float4*>(part + (HID * HID) + idx);
  float4 s2 = *reinterpret_cast<const float4*>(part + 2 * (HID * HID) + idx);
  float4 s3 = *reinterpret_cast<const float4*>(part + 3 * (HID * HID) + idx);
  __hip_bfloat16 tmp[4] = {__float2bfloat16(s0.x + s1.x + s2.x + s3.x),
                           __float2bfloat16(s0.y + s1.y + s2.y + s3.y),
                           __float2bfloat16(s0.z + s1.z + s2.z + s3.z),
                           __float2bfloat16(s0.w + s1.w + s2.w + s3.w)};
  *reinterpret_cast<ushort4*>(wmid_bf + idx) =
      *reinterpret_cast<const ushort4*>(tmp);
}

// ============ T = hs @ Wmid  (NT core, NF=2: 256x128 tiles) ============
// grid (1024/128=8, 8192/256=32)
__global__ __launch_bounds__(512, 2) void t_gemm(
    const __hip_bfloat16* __restrict__ hs_bf,
    const __hip_bfloat16* __restrict__ wmid_bf,
    __hip_bfloat16* __restrict__ T) {
  extern __shared__ char smem[];
  __hip_bfloat16* lds = reinterpret_cast<__hip_bfloat16*>(smem);
  f32x4 acc[8][2];
#pragma unroll
  for (int m = 0; m < 8; ++m)
#pragma unroll
    for (int n = 0; n < 2; ++n) acc[m][n] = (f32x4){0.f, 0.f, 0.f, 0.f};

  gemm_core<16, 2>(hs_bf + (size_t)blockIdx.y * 256 * HID,
                   wmid_bf + (size_t)blockIdx.x * 128 * HID, HID, HID, lds,
                   acc);

  const int t = threadIdx.x, wid = t >> 6, l = t & 63;
  const int wr = wid >> 2, wcn = wid & 3;
  const int lr = l & 15, lg = l >> 4;
#pragma unroll
  for (int m = 0; m < 8; ++m)
#pragma unroll
    for (int n = 0; n < 2; ++n) {
      const int col = blockIdx.x * 128 + wcn * 32 + n * 16 + lr;
#pragma unroll
      for (int r = 0; r < 4; ++r) {
        const int row = blockIdx.y * 256 + wr * 128 + m * 16 + lg * 4 + r;
        T[(size_t)row * HID + col] = __float2bfloat16(acc[m][n][r]);
      }
    }
}

// ====== scores: out[b] = (T hs^T + u 1^T + 1 w^T)/128 * masks ==========
// grid (S/256, S/256, BATCH)
__global__ __launch_bounds__(512, 2) void scores_gemm(
    const __hip_bfloat16* __restrict__ T, const __hip_bfloat16* __restrict__ hs_bf,
    const float* __restrict__ mask, const float* __restrict__ u,
    const float* __restrict__ w, float* __restrict__ out) {
  extern __shared__ char smem[];
  __hip_bfloat16* lds = reinterpret_cast<__hip_bfloat16*>(smem);
  const int b = blockIdx.z;
  const int bm = blockIdx.y, bn = blockIdx.x;

  f32x4 acc[8][4];
#pragma unroll
  for (int m = 0; m < 8; ++m)
#pragma unroll
    for (int n = 0; n < 4; ++n) acc[m][n] = (f32x4){0.f, 0.f, 0.f, 0.f};

  gemm_core<16, 4>(T + ((size_t)b * S_LEN + bm * 256) * HID,
                   hs_bf + ((size_t)b * S_LEN + bn * 256) * HID, HID, HID,
                   lds, acc);

  const int t = threadIdx.x, wid = t >> 6, l = t & 63;
  const int wr = wid >> 2, wcn = wid & 3;
  const int lr = l & 15, lg = l >> 4;
  const float inv = 1.0f / 128.0f;   // 1/sqrt(64) * 1/16 heads
#pragma unroll
  for (int m = 0; m < 8; ++m)
#pragma unroll
    for (int n = 0; n < 4; ++n) {
      const int col = bn * 256 + wcn * 64 + n * 16 + lr;
      const float mc = mask[b * S_LEN + col];
      const float wadd = w[b * S_LEN + col];
#pragma unroll
      for (int r = 0; r < 4; ++r) {
        const int row = bm * 256 + wr * 128 + m * 16 + lg * 4 + r;
        const float mr = mask[b * S_LEN + row];
        const float uadd = u[b * S_LEN + row];
        out[(size_t)b * S_LEN * S_LEN + (size_t)row * S_LEN + col] =
            (acc[m][n][r] + uadd + wadd) * inv * mc * mr;
      }
    }
}

extern "C" void kernel_launch(void* const* d_in, const int* in_sizes, int n_in,
                              void* d_out, int out_size, void* d_ws,
                              size_t ws_size, hipStream_t stream) {
  const float* hs   = (const float*)d_in[0];
  const float* mask = (const float*)d_in[1];
  const float* Wq   = (const float*)d_in[2];
  const float* bq   = (const float*)d_in[3];
  const float* Wk   = (const float*)d_in[4];
  const float* bk   = (const float*)d_in[5];
  float* out = (float*)d_out;

  char* ws = (char*)d_ws;
  __hip_bfloat16* hs_bf   = (__hip_bfloat16*)(ws);               // 16 MB
  float*          wmid_p  = (float*)(ws + 16777216);             // 16 MB (steps 4-5)
  __hip_bfloat16* T_bf    = (__hip_bfloat16*)(ws + 16777216);    // same region (steps 6-7)
  __hip_bfloat16* WqT     = (__hip_bfloat16*)(ws + 33554432);    //  2 MB
  __hip_bfloat16* WkT     = (__hip_bfloat16*)(ws + 35651584);    //  2 MB
  __hip_bfloat16* wmid_bf = (__hip_bfloat16*)(ws + 37748736);    //  2 MB
  float*          a1      = (float*)(ws + 39845888);             //  4 KB
  float*          a2      = (float*)(ws + 39849984);             //  4 KB
  float*          cbuf    = (float*)(ws + 39854080);             //  4 KB
  float*          uvec    = (float*)(ws + 39858176);             // 32 KB
  float*          wvec    = (float*)(ws + 39890944);             // 32 KB
  // total ws use: ~38.1 MB

  (void)hipFuncSetAttribute((const void*)wmid_gemm,
                            hipFuncAttributeMaxDynamicSharedMemorySize, 131072);
  (void)hipFuncSetAttribute((const void*)t_gemm,
                            hipFuncAttributeMaxDynamicSharedMemorySize, 98304);
  (void)hipFuncSetAttribute((const void*)scores_gemm,
                            hipFuncAttributeMaxDynamicSharedMemorySize, 131072);

  hipLaunchKernelGGL(transpose_convert, dim3(32, 32, 2), dim3(256), 0, stream,
                     Wq, Wk, WqT, WkT);
  hipLaunchKernelGGL(bias_stage1, dim3(512), dim3(256), 0, stream,
                     WqT, WkT, bq, bk, a1, a2, cbuf);
  hipLaunchKernelGGL(convert_hs, dim3(M_ROWS), dim3(256), 0, stream,
                     hs, a1, a2, cbuf, hs_bf, uvec, wvec);
  hipLaunchKernelGGL(wmid_gemm, dim3(4, 4, 4), dim3(512), 131072, stream,
                     WkT, WqT, wmid_p);
  hipLaunchKernelGGL(wmid_reduce, dim3(1024), dim3(256), 0, stream,
                     wmid_p, wmid_bf);
  hipLaunchKernelGGL(t_gemm, dim3(HID / 128, M_ROWS / 256), dim3(512), 98304,
                     stream, hs_bf, wmid_bf, T_bf);
  hipLaunchKernelGGL(scores_gemm, dim3(S_LEN / 256, S_LEN / 256, BATCH),
                     dim3(512), 131072, stream, T_bf, hs_bf, mask, uvec, wvec,
                     out);
}